// Round 1
// baseline (811.769 us; speedup 1.0000x reference)
//
#include <hip/hip_runtime.h>
#include <hip/hip_bf16.h>

#define AS1 __attribute__((address_space(1)))
#define AS3 __attribute__((address_space(3)))

typedef __bf16 bf16x8_t __attribute__((ext_vector_type(8)));
typedef float f32x4_t __attribute__((ext_vector_type(4)));
typedef unsigned short ushort_t;
typedef unsigned int uint_t;

static __device__ __forceinline__ float bl(uint_t u) { return __uint_as_float(u << 16); }
static __device__ __forceinline__ float bh(uint_t u) { return __uint_as_float(u & 0xffff0000u); }
static __device__ __forceinline__ ushort_t f2b(float f) {
    __hip_bfloat16 h = __float2bfloat16(f);
    return __builtin_bit_cast(unsigned short, h);
}

// ---------------------------------------------------------------- cast f32->bf16
__global__ __launch_bounds__(256) void cast_f32_bf16(const float* __restrict__ in,
                                                     ushort_t* __restrict__ out, int n4) {
    int i = blockIdx.x * 256 + threadIdx.x;
    if (i < n4) {
        float4 v = ((const float4*)in)[i];
        ushort4 o;
        o.x = f2b(v.x); o.y = f2b(v.y); o.z = f2b(v.z); o.w = f2b(v.w);
        ((ushort4*)out)[i] = o;
    }
}

// ---------------------------------------------------------------- bf16 MFMA GEMM
// C(MxN) = A(MxK) @ B^T (B stored NxK row-major), epilogue per FLAGS.
#define EPI_BIAS 1
#define EPI_RELU 2
#define EPI_RES  4
#define EPI_OUTF 8
#define EPI_OUTB 16

template <int F>
__global__ __launch_bounds__(256, 2) void gemm_bt(const ushort_t* __restrict__ A,
                                                  const ushort_t* __restrict__ B,
                                                  const float* __restrict__ bias,
                                                  const float* __restrict__ res,
                                                  float* __restrict__ outf,
                                                  ushort_t* __restrict__ outb,
                                                  int M, int N, int K) {
    __shared__ ushort_t la[128 * 32];
    __shared__ ushort_t lb[128 * 32];
    const int t = threadIdx.x;
    const int n0 = blockIdx.x * 128;
    const int m0 = blockIdx.y * 128;
    const int lane = t & 63;
    const int w = t >> 6;
    const int wr = w >> 1, wc = w & 1;
    const int r16 = lane & 15, kq = lane >> 4;

    const int srow = t >> 2;   // 0..63 staging row (+64 for p=1)
    const int scg = t & 3;     // 16B chunk within 32-col row

    f32x4_t acc[4][4] = {};

    const size_t arow0 = (size_t)(m0 + srow) * K + scg * 8;
    const size_t brow0 = (size_t)(n0 + srow) * K + scg * 8;

    for (int k0 = 0; k0 < K; k0 += 32) {
#pragma unroll
        for (int p = 0; p < 2; ++p) {
            const ushort_t* ga = A + arow0 + (size_t)p * 64 * K + k0;
            const ushort_t* gb = B + brow0 + (size_t)p * 64 * K + k0;
            __builtin_amdgcn_global_load_lds((AS1 void*)ga, (AS3 void*)(la + (t + 256 * p) * 8), 16, 0, 0);
            __builtin_amdgcn_global_load_lds((AS1 void*)gb, (AS3 void*)(lb + (t + 256 * p) * 8), 16, 0, 0);
        }
        __syncthreads();
        bf16x8_t af[4], bfr[4];
#pragma unroll
        for (int mi = 0; mi < 4; ++mi)
            af[mi] = *(const bf16x8_t*)(la + (wr * 64 + mi * 16 + r16) * 32 + kq * 8);
#pragma unroll
        for (int ni = 0; ni < 4; ++ni)
            bfr[ni] = *(const bf16x8_t*)(lb + (wc * 64 + ni * 16 + r16) * 32 + kq * 8);
#pragma unroll
        for (int mi = 0; mi < 4; ++mi)
#pragma unroll
            for (int ni = 0; ni < 4; ++ni)
                acc[mi][ni] = __builtin_amdgcn_mfma_f32_16x16x32_bf16(af[mi], bfr[ni], acc[mi][ni], 0, 0, 0);
        __syncthreads();
    }

#pragma unroll
    for (int mi = 0; mi < 4; ++mi) {
#pragma unroll
        for (int ni = 0; ni < 4; ++ni) {
            const int row = m0 + wr * 64 + mi * 16 + kq * 4;
            const int col = n0 + wc * 64 + ni * 16 + r16;
            float bv = (F & EPI_BIAS) ? bias[col] : 0.f;
#pragma unroll
            for (int i = 0; i < 4; ++i) {
                float v = acc[mi][ni][i] + bv;
                const size_t off = (size_t)(row + i) * N + col;
                if (F & EPI_RES) v += res[off];
                if (F & EPI_RELU) v = fmaxf(v, 0.f);
                if (F & EPI_OUTF) outf[off] = v;
                if (F & EPI_OUTB) outb[off] = f2b(v);
            }
        }
    }
}

// ---------------------------------------------------------------- banded flash attention
// qkv: (B*S, 3072) bf16 rows [q | k | v], head h owns cols h*64..h*64+63 of each third.
// One wave per 64 queries; lane = one query; online softmax over its +/-128 window.
__global__ __launch_bounds__(64) void flash_banded(const ushort_t* __restrict__ qkv,
                                                   ushort_t* __restrict__ attn) {
    const int S = 2048, W = 128;
    const int h = blockIdx.y;
    const int bb = blockIdx.z;
    const int qw = blockIdx.x * 64;
    const int lane = threadIdx.x;
    const int i = qw + lane;

    const ushort_t* base = qkv + (size_t)bb * S * 3072 + (size_t)h * 64;

    float q[64];
    {
        const uint4* qp = (const uint4*)(base + (size_t)i * 3072);
#pragma unroll
        for (int cg = 0; cg < 8; ++cg) {
            uint4 u = qp[cg];
            q[cg * 8 + 0] = bl(u.x) * 0.125f; q[cg * 8 + 1] = bh(u.x) * 0.125f;
            q[cg * 8 + 2] = bl(u.y) * 0.125f; q[cg * 8 + 3] = bh(u.y) * 0.125f;
            q[cg * 8 + 4] = bl(u.z) * 0.125f; q[cg * 8 + 5] = bh(u.z) * 0.125f;
            q[cg * 8 + 6] = bl(u.w) * 0.125f; q[cg * 8 + 7] = bh(u.w) * 0.125f;
        }
    }
    float O[64];
#pragma unroll
    for (int d = 0; d < 64; ++d) O[d] = 0.f;
    float m = -1e30f, l = 0.f;

    int jlo = qw - W; if (jlo < 0) jlo = 0;
    int jhi = qw + 63 + W; if (jhi > S - 1) jhi = S - 1;

    for (int j = jlo; j <= jhi; ++j) {
        const uint4* kp = (const uint4*)(base + 1024 + (size_t)j * 3072);
        const uint4* vp = (const uint4*)(base + 2048 + (size_t)j * 3072);
        float sp[8];
#pragma unroll
        for (int cg = 0; cg < 8; ++cg) {
            uint4 u = kp[cg];
            float t0 = q[cg * 8 + 0] * bl(u.x);
            t0 = fmaf(q[cg * 8 + 1], bh(u.x), t0);
            t0 = fmaf(q[cg * 8 + 2], bl(u.y), t0);
            t0 = fmaf(q[cg * 8 + 3], bh(u.y), t0);
            t0 = fmaf(q[cg * 8 + 4], bl(u.z), t0);
            t0 = fmaf(q[cg * 8 + 5], bh(u.z), t0);
            t0 = fmaf(q[cg * 8 + 6], bl(u.w), t0);
            t0 = fmaf(q[cg * 8 + 7], bh(u.w), t0);
            sp[cg] = t0;
        }
        float s = ((sp[0] + sp[1]) + (sp[2] + sp[3])) + ((sp[4] + sp[5]) + (sp[6] + sp[7]));

        bool valid = (j >= i - W) && (j <= i + W);
        float sv = valid ? s : -1e30f;
        float mn = fmaxf(m, sv);
        float alpha = __expf(m - mn);          // ==1 while everything still masked (O==0, safe)
        float p = valid ? __expf(s - mn) : 0.f;
        l = l * alpha + p;
        m = mn;

#pragma unroll
        for (int cg = 0; cg < 8; ++cg) {
            uint4 u = vp[cg];
            O[cg * 8 + 0] = fmaf(O[cg * 8 + 0], alpha, p * bl(u.x));
            O[cg * 8 + 1] = fmaf(O[cg * 8 + 1], alpha, p * bh(u.x));
            O[cg * 8 + 2] = fmaf(O[cg * 8 + 2], alpha, p * bl(u.y));
            O[cg * 8 + 3] = fmaf(O[cg * 8 + 3], alpha, p * bh(u.y));
            O[cg * 8 + 4] = fmaf(O[cg * 8 + 4], alpha, p * bl(u.z));
            O[cg * 8 + 5] = fmaf(O[cg * 8 + 5], alpha, p * bh(u.z));
            O[cg * 8 + 6] = fmaf(O[cg * 8 + 6], alpha, p * bl(u.w));
            O[cg * 8 + 7] = fmaf(O[cg * 8 + 7], alpha, p * bh(u.w));
        }
    }

    float inv = 1.0f / l;
    uint4* op = (uint4*)(attn + ((size_t)(bb * S + i)) * 1024 + (size_t)h * 64);
#pragma unroll
    for (int cg = 0; cg < 8; ++cg) {
        uint4 o;
        o.x = (uint_t)f2b(O[cg * 8 + 0] * inv) | ((uint_t)f2b(O[cg * 8 + 1] * inv) << 16);
        o.y = (uint_t)f2b(O[cg * 8 + 2] * inv) | ((uint_t)f2b(O[cg * 8 + 3] * inv) << 16);
        o.z = (uint_t)f2b(O[cg * 8 + 4] * inv) | ((uint_t)f2b(O[cg * 8 + 5] * inv) << 16);
        o.w = (uint_t)f2b(O[cg * 8 + 6] * inv) | ((uint_t)f2b(O[cg * 8 + 7] * inv) << 16);
        op[cg] = o;
    }
}

// ---------------------------------------------------------------- LayerNorm (D=1024), block per row
__global__ __launch_bounds__(256) void layernorm_k(const float* __restrict__ in,
                                                   const float* __restrict__ g,
                                                   const float* __restrict__ bta,
                                                   float* __restrict__ outf,
                                                   ushort_t* __restrict__ outb) {
    const int row = blockIdx.x;
    const int t = threadIdx.x;
    const float4 v = ((const float4*)(in + (size_t)row * 1024))[t];
    float s = v.x + v.y + v.z + v.w;
    float s2 = v.x * v.x + v.y * v.y + v.z * v.z + v.w * v.w;
#pragma unroll
    for (int off = 32; off > 0; off >>= 1) {
        s += __shfl_down(s, off);
        s2 += __shfl_down(s2, off);
    }
    __shared__ float red[8];
    const int w = t >> 6, lane = t & 63;
    if (lane == 0) { red[w] = s; red[4 + w] = s2; }
    __syncthreads();
    float S1 = red[0] + red[1] + red[2] + red[3];
    float S2 = red[4] + red[5] + red[6] + red[7];
    float mean = S1 * (1.f / 1024.f);
    float var = S2 * (1.f / 1024.f) - mean * mean;
    float r = rsqrtf(var + 1e-5f);
    float4 gg = ((const float4*)g)[t];
    float4 bb = ((const float4*)bta)[t];
    float4 o;
    o.x = (v.x - mean) * r * gg.x + bb.x;
    o.y = (v.y - mean) * r * gg.y + bb.y;
    o.z = (v.z - mean) * r * gg.z + bb.z;
    o.w = (v.w - mean) * r * gg.w + bb.w;
    ((float4*)(outf + (size_t)row * 1024))[t] = o;
    if (outb) {
        ushort4 ob;
        ob.x = f2b(o.x); ob.y = f2b(o.y); ob.z = f2b(o.z); ob.w = f2b(o.w);
        ((ushort4*)(outb + (size_t)row * 1024))[t] = ob;
    }
}

// ---------------------------------------------------------------- launch
extern "C" void kernel_launch(void* const* d_in, const int* in_sizes, int n_in,
                              void* d_out, int out_size, void* d_ws, size_t ws_size,
                              hipStream_t stream) {
    const float* x          = (const float*)d_in[0];
    const float* in_proj_w  = (const float*)d_in[1];
    const float* in_proj_b  = (const float*)d_in[2];
    const float* out_proj_w = (const float*)d_in[3];
    const float* out_proj_b = (const float*)d_in[4];
    const float* ln1_g      = (const float*)d_in[5];
    const float* ln1_b      = (const float*)d_in[6];
    const float* w1         = (const float*)d_in[7];
    const float* b1         = (const float*)d_in[8];
    const float* w2         = (const float*)d_in[9];
    const float* b2         = (const float*)d_in[10];
    const float* ln2_g      = (const float*)d_in[11];
    const float* ln2_b      = (const float*)d_in[12];
    // d_in[13] = window (always 128 for this problem; hardcoded in flash kernel)

    char* ws = (char*)d_ws;
    ushort_t* xb    = (ushort_t*)(ws + (0ull << 20));    //  8 MB: x bf16       (4096x1024)
    ushort_t* wqkvb = (ushort_t*)(ws + (8ull << 20));    //  6 MB: in_proj_w    (3072x1024)
    ushort_t* woutb = (ushort_t*)(ws + (14ull << 20));   //  2 MB: out_proj_w   (1024x1024)
    ushort_t* w1b   = (ushort_t*)(ws + (16ull << 20));   //  8 MB: w1           (4096x1024)
    ushort_t* w2b   = (ushort_t*)(ws + (24ull << 20));   //  8 MB: w2           (1024x4096)
    ushort_t* qkvb  = (ushort_t*)(ws + (32ull << 20));   // 24 MB: qkv bf16     (4096x3072)
    ushort_t* attnb = (ushort_t*)(ws + (56ull << 20));   //  8 MB: attn bf16    (4096x1024)
    float*    y1    = (float*)(ws + (64ull << 20));      // 16 MB: residual1 / residual2 f32
    float*    x2f   = (float*)(ws + (80ull << 20));      // 16 MB: x2 f32
    ushort_t* x2b   = (ushort_t*)(ws + (96ull << 20));   //  8 MB: x2 bf16
    ushort_t* hb    = (ushort_t*)(ws + (104ull << 20));  // 32 MB: relu hidden  (4096x4096)
    (void)in_sizes; (void)n_in; (void)out_size; (void)ws_size;

    // casts
    cast_f32_bf16<<<4096, 256, 0, stream>>>(x, xb, 1048576);
    cast_f32_bf16<<<3072, 256, 0, stream>>>(in_proj_w, wqkvb, 786432);
    cast_f32_bf16<<<1024, 256, 0, stream>>>(out_proj_w, woutb, 262144);
    cast_f32_bf16<<<4096, 256, 0, stream>>>(w1, w1b, 1048576);
    cast_f32_bf16<<<4096, 256, 0, stream>>>(w2, w2b, 1048576);

    // qkv = x @ in_proj_w.T + b   -> bf16
    gemm_bt<EPI_BIAS | EPI_OUTB><<<dim3(24, 32), 256, 0, stream>>>(
        xb, wqkvb, in_proj_b, nullptr, nullptr, qkvb, 4096, 3072, 1024);

    // banded attention -> attnb bf16
    flash_banded<<<dim3(32, 16, 2), 64, 0, stream>>>(qkvb, attnb);

    // y1 = x + attn @ out_proj_w.T + b  -> f32
    gemm_bt<EPI_BIAS | EPI_RES | EPI_OUTF><<<dim3(8, 32), 256, 0, stream>>>(
        attnb, woutb, out_proj_b, x, y1, nullptr, 4096, 1024, 1024);

    // x2 = LN1(y1) -> f32 + bf16
    layernorm_k<<<4096, 256, 0, stream>>>(y1, ln1_g, ln1_b, x2f, x2b);

    // h = relu(x2 @ w1.T + b1) -> bf16
    gemm_bt<EPI_BIAS | EPI_RELU | EPI_OUTB><<<dim3(32, 32), 256, 0, stream>>>(
        x2b, w1b, b1, nullptr, nullptr, hb, 4096, 4096, 1024);

    // y2 = x2 + h @ w2.T + b2 -> f32 (reuse y1 buffer)
    gemm_bt<EPI_BIAS | EPI_RES | EPI_OUTF><<<dim3(8, 32), 256, 0, stream>>>(
        hb, w2b, b2, x2f, y1, nullptr, 4096, 1024, 4096);

    // out = LN2(y2) -> f32 d_out
    layernorm_k<<<4096, 256, 0, stream>>>(y1, ln2_g, ln2_b, (float*)d_out, nullptr);
}

// Round 2
// 357.934 us; speedup vs baseline: 2.2679x; 2.2679x over previous
//
#include <hip/hip_runtime.h>
#include <hip/hip_bf16.h>

#define AS1 __attribute__((address_space(1)))
#define AS3 __attribute__((address_space(3)))

typedef __bf16 bf16x8_t __attribute__((ext_vector_type(8)));
typedef float f32x4_t __attribute__((ext_vector_type(4)));
typedef unsigned short ushort_t;
typedef unsigned int uint_t;

static __device__ __forceinline__ ushort_t f2b(float f) {
    __hip_bfloat16 h = __float2bfloat16(f);
    return __builtin_bit_cast(unsigned short, h);
}

// ---------------------------------------------------------------- cast f32->bf16
__global__ __launch_bounds__(256) void cast_f32_bf16(const float* __restrict__ in,
                                                     ushort_t* __restrict__ out, int n4) {
    int i = blockIdx.x * 256 + threadIdx.x;
    if (i < n4) {
        float4 v = ((const float4*)in)[i];
        ushort4 o;
        o.x = f2b(v.x); o.y = f2b(v.y); o.z = f2b(v.z); o.w = f2b(v.w);
        ((ushort4*)out)[i] = o;
    }
}

// ---------------------------------------------------------------- bf16 MFMA GEMM
// C(MxN) = A(MxK) @ B^T (B stored NxK row-major), epilogue per FLAGS.
#define EPI_BIAS 1
#define EPI_RELU 2
#define EPI_RES  4
#define EPI_OUTF 8
#define EPI_OUTB 16

template <int F>
__global__ __launch_bounds__(256, 2) void gemm_bt(const ushort_t* __restrict__ A,
                                                  const ushort_t* __restrict__ B,
                                                  const float* __restrict__ bias,
                                                  const float* __restrict__ res,
                                                  float* __restrict__ outf,
                                                  ushort_t* __restrict__ outb,
                                                  int M, int N, int K) {
    __shared__ ushort_t la[128 * 32];
    __shared__ ushort_t lb[128 * 32];
    const int t = threadIdx.x;
    const int n0 = blockIdx.x * 128;
    const int m0 = blockIdx.y * 128;
    const int lane = t & 63;
    const int w = t >> 6;
    const int wr = w >> 1, wc = w & 1;
    const int r16 = lane & 15, kq = lane >> 4;

    const int srow = t >> 2;   // 0..63 staging row (+64 for p=1)
    const int scg = t & 3;     // 16B chunk within 32-col row

    f32x4_t acc[4][4] = {};

    const size_t arow0 = (size_t)(m0 + srow) * K + scg * 8;
    const size_t brow0 = (size_t)(n0 + srow) * K + scg * 8;

    for (int k0 = 0; k0 < K; k0 += 32) {
#pragma unroll
        for (int p = 0; p < 2; ++p) {
            const ushort_t* ga = A + arow0 + (size_t)p * 64 * K + k0;
            const ushort_t* gb = B + brow0 + (size_t)p * 64 * K + k0;
            __builtin_amdgcn_global_load_lds((AS1 void*)ga, (AS3 void*)(la + (t + 256 * p) * 8), 16, 0, 0);
            __builtin_amdgcn_global_load_lds((AS1 void*)gb, (AS3 void*)(lb + (t + 256 * p) * 8), 16, 0, 0);
        }
        __syncthreads();
        bf16x8_t af[4], bfr[4];
#pragma unroll
        for (int mi = 0; mi < 4; ++mi)
            af[mi] = *(const bf16x8_t*)(la + (wr * 64 + mi * 16 + r16) * 32 + kq * 8);
#pragma unroll
        for (int ni = 0; ni < 4; ++ni)
            bfr[ni] = *(const bf16x8_t*)(lb + (wc * 64 + ni * 16 + r16) * 32 + kq * 8);
#pragma unroll
        for (int mi = 0; mi < 4; ++mi)
#pragma unroll
            for (int ni = 0; ni < 4; ++ni)
                acc[mi][ni] = __builtin_amdgcn_mfma_f32_16x16x32_bf16(af[mi], bfr[ni], acc[mi][ni], 0, 0, 0);
        __syncthreads();
    }

#pragma unroll
    for (int mi = 0; mi < 4; ++mi) {
#pragma unroll
        for (int ni = 0; ni < 4; ++ni) {
            const int row = m0 + wr * 64 + mi * 16 + kq * 4;
            const int col = n0 + wc * 64 + ni * 16 + r16;
            float bv = (F & EPI_BIAS) ? bias[col] : 0.f;
#pragma unroll
            for (int i = 0; i < 4; ++i) {
                float v = acc[mi][ni][i] + bv;
                const size_t off = (size_t)(row + i) * N + col;
                if (F & EPI_RES) v += res[off];
                if (F & EPI_RELU) v = fmaxf(v, 0.f);
                if (F & EPI_OUTF) outf[off] = v;
                if (F & EPI_OUTB) outb[off] = f2b(v);
            }
        }
    }
}

// ---------------------------------------------------------------- MFMA banded flash attention
// qkv: (B*S, 3072) bf16 rows [q | k | v], head h owns cols h*64..h*64+63 of each third.
// Block = 64-query tile for one (b,h); 4 waves, wave w owns queries q0+16w..+15.
// Iterate 5 aligned 64-key tiles (band +/-128). Tiles are 64-aligned -> fully
// inside or outside [0,S); only the band mask is needed.
__global__ __launch_bounds__(256, 4) void flash_mfma(const ushort_t* __restrict__ qkv,
                                                     ushort_t* __restrict__ attn) {
    const int S = 2048;
    const int h = blockIdx.y, bb = blockIdx.z;
    const int q0 = blockIdx.x * 64;
    const int t = threadIdx.x;
    const int w = t >> 6, lane = t & 63;
    const int r16 = lane & 15, g = lane >> 4;

    // K natural [key][dim], stride 72 bf16 (144B: 16B-aligned rows, bank-balanced b128 frag reads)
    __shared__ ushort_t lk[64 * 72];
    // V natural [key][dim], stride 68 bf16 (136B: 8-row delta = 16 banks -> ~2-way on u16 frag gathers)
    __shared__ ushort_t lv[64 * 68];
    // P per-wave private [q][key], stride 72
    __shared__ ushort_t lp[4 * 16 * 72];

    const ushort_t* base = qkv + (size_t)bb * S * 3072 + (size_t)h * 64;

    // Q A-fragments (registers, loaded once): lane holds Q[q0+16w+r16][kc*32 + g*8 + j]
    bf16x8_t qa[2];
    {
        const ushort_t* qrow = base + (size_t)(q0 + 16 * w + r16) * 3072;
        qa[0] = *(const bf16x8_t*)(qrow + g * 8);
        qa[1] = *(const bf16x8_t*)(qrow + 32 + g * 8);
    }

    f32x4_t O[4] = {};                       // 16q x 64d in C layout (dd subtiles)
    float mrow[4] = {-1e30f, -1e30f, -1e30f, -1e30f};
    float lrow[4] = {0.f, 0.f, 0.f, 0.f};

    for (int it = 0; it < 5; ++it) {
        const int kt0 = q0 - 128 + 64 * it;
        if (kt0 < 0 || kt0 >= S) continue;   // block-uniform skip

        // ---- stage K,V tile (256 threads x 2 chunks of 16B each)
#pragma unroll
        for (int pass = 0; pass < 2; ++pass) {
            const int c = t + 256 * pass;    // 0..511
            const int key = c >> 3, dc = c & 7;
            const ushort_t* src = base + (size_t)(kt0 + key) * 3072 + dc * 8;
            uint4 kk = *(const uint4*)(src + 1024);
            uint4 vv = *(const uint4*)(src + 2048);
            *(uint4*)(lk + key * 72 + dc * 8) = kk;
            uint2* vd = (uint2*)(lv + key * 68 + dc * 8);
            vd[0] = make_uint2(vv.x, vv.y);
            vd[1] = make_uint2(vv.z, vv.w);
        }
        __syncthreads();

        // ---- QK^T: S-tile 16q x 64k, C layout, 8 MFMAs
        f32x4_t s[4];
#pragma unroll
        for (int sub = 0; sub < 4; ++sub) {
            const ushort_t* krow = lk + (16 * sub + r16) * 72;
            bf16x8_t kb0 = *(const bf16x8_t*)(krow + g * 8);
            bf16x8_t kb1 = *(const bf16x8_t*)(krow + 32 + g * 8);
            f32x4_t z = {};
            z = __builtin_amdgcn_mfma_f32_16x16x32_bf16(qa[0], kb0, z, 0, 0, 0);
            z = __builtin_amdgcn_mfma_f32_16x16x32_bf16(qa[1], kb1, z, 0, 0, 0);
            s[sub] = z;
        }

        // ---- online softmax per row (row = g*4 + reg)
        float alpha[4];
#pragma unroll
        for (int reg = 0; reg < 4; ++reg) {
            const int i = q0 + 16 * w + g * 4 + reg;
            float rm = -1e30f;
#pragma unroll
            for (int sub = 0; sub < 4; ++sub) {
                const int j = kt0 + 16 * sub + r16;
                const int d = i - j;
                const bool valid = (d <= 128) && (d >= -128);
                float v = valid ? s[sub][reg] * 0.125f : -1e30f;
                s[sub][reg] = v;
                rm = fmaxf(rm, v);
            }
#pragma unroll
            for (int msk = 1; msk < 16; msk <<= 1) rm = fmaxf(rm, __shfl_xor(rm, msk));
            const float mnew = fmaxf(mrow[reg], rm);
            alpha[reg] = __expf(mrow[reg] - mnew);
            mrow[reg] = mnew;
            float rs = 0.f;
#pragma unroll
            for (int sub = 0; sub < 4; ++sub) {
                float p = __expf(s[sub][reg] - mnew);
                s[sub][reg] = p;
                rs += p;
            }
#pragma unroll
            for (int msk = 1; msk < 16; msk <<= 1) rs += __shfl_xor(rs, msk);
            lrow[reg] = lrow[reg] * alpha[reg] + rs;
#pragma unroll
            for (int dd = 0; dd < 4; ++dd) O[dd][reg] *= alpha[reg];
        }

        // ---- P: C layout -> LDS [q][key] (wave-private; no barrier needed)
        ushort_t* pw = lp + w * 16 * 72;
#pragma unroll
        for (int sub = 0; sub < 4; ++sub)
#pragma unroll
            for (int reg = 0; reg < 4; ++reg)
                pw[(g * 4 + reg) * 72 + 16 * sub + r16] = f2b(s[sub][reg]);

        // ---- PV: O += P @ V, 8 MFMAs
        bf16x8_t pa0 = *(const bf16x8_t*)(pw + r16 * 72 + g * 8);
        bf16x8_t pa1 = *(const bf16x8_t*)(pw + r16 * 72 + 32 + g * 8);
        const __bf16* lvb = (const __bf16*)lv;
#pragma unroll
        for (int dd = 0; dd < 4; ++dd) {
            bf16x8_t vb0, vb1;
#pragma unroll
            for (int j = 0; j < 8; ++j) {
                vb0[j] = lvb[(g * 8 + j) * 68 + dd * 16 + r16];
                vb1[j] = lvb[(32 + g * 8 + j) * 68 + dd * 16 + r16];
            }
            O[dd] = __builtin_amdgcn_mfma_f32_16x16x32_bf16(pa0, vb0, O[dd], 0, 0, 0);
            O[dd] = __builtin_amdgcn_mfma_f32_16x16x32_bf16(pa1, vb1, O[dd], 0, 0, 0);
        }
        __syncthreads();
    }

    // ---- epilogue: O /= l, write bf16
#pragma unroll
    for (int reg = 0; reg < 4; ++reg) {
        const float inv = 1.0f / lrow[reg];
        const int i = q0 + 16 * w + g * 4 + reg;
        ushort_t* orow = attn + ((size_t)(bb * S + i)) * 1024 + (size_t)h * 64;
#pragma unroll
        for (int dd = 0; dd < 4; ++dd)
            orow[dd * 16 + r16] = f2b(O[dd][reg] * inv);
    }
}

// ---------------------------------------------------------------- LayerNorm (D=1024), block per row
__global__ __launch_bounds__(256) void layernorm_k(const float* __restrict__ in,
                                                   const float* __restrict__ g,
                                                   const float* __restrict__ bta,
                                                   float* __restrict__ outf,
                                                   ushort_t* __restrict__ outb) {
    const int row = blockIdx.x;
    const int t = threadIdx.x;
    const float4 v = ((const float4*)(in + (size_t)row * 1024))[t];
    float s = v.x + v.y + v.z + v.w;
    float s2 = v.x * v.x + v.y * v.y + v.z * v.z + v.w * v.w;
#pragma unroll
    for (int off = 32; off > 0; off >>= 1) {
        s += __shfl_down(s, off);
        s2 += __shfl_down(s2, off);
    }
    __shared__ float red[8];
    const int w = t >> 6, lane = t & 63;
    if (lane == 0) { red[w] = s; red[4 + w] = s2; }
    __syncthreads();
    float S1 = red[0] + red[1] + red[2] + red[3];
    float S2 = red[4] + red[5] + red[6] + red[7];
    float mean = S1 * (1.f / 1024.f);
    float var = S2 * (1.f / 1024.f) - mean * mean;
    float r = rsqrtf(var + 1e-5f);
    float4 gg = ((const float4*)g)[t];
    float4 bb = ((const float4*)bta)[t];
    float4 o;
    o.x = (v.x - mean) * r * gg.x + bb.x;
    o.y = (v.y - mean) * r * gg.y + bb.y;
    o.z = (v.z - mean) * r * gg.z + bb.z;
    o.w = (v.w - mean) * r * gg.w + bb.w;
    ((float4*)(outf + (size_t)row * 1024))[t] = o;
    if (outb) {
        ushort4 ob;
        ob.x = f2b(o.x); ob.y = f2b(o.y); ob.z = f2b(o.z); ob.w = f2b(o.w);
        ((ushort4*)(outb + (size_t)row * 1024))[t] = ob;
    }
}

// ---------------------------------------------------------------- launch
extern "C" void kernel_launch(void* const* d_in, const int* in_sizes, int n_in,
                              void* d_out, int out_size, void* d_ws, size_t ws_size,
                              hipStream_t stream) {
    const float* x          = (const float*)d_in[0];
    const float* in_proj_w  = (const float*)d_in[1];
    const float* in_proj_b  = (const float*)d_in[2];
    const float* out_proj_w = (const float*)d_in[3];
    const float* out_proj_b = (const float*)d_in[4];
    const float* ln1_g      = (const float*)d_in[5];
    const float* ln1_b      = (const float*)d_in[6];
    const float* w1         = (const float*)d_in[7];
    const float* b1         = (const float*)d_in[8];
    const float* w2         = (const float*)d_in[9];
    const float* b2         = (const float*)d_in[10];
    const float* ln2_g      = (const float*)d_in[11];
    const float* ln2_b      = (const float*)d_in[12];
    // d_in[13] = window (always 128 for this problem; hardcoded in flash kernel)

    char* ws = (char*)d_ws;
    ushort_t* xb    = (ushort_t*)(ws + (0ull << 20));    //  8 MB: x bf16       (4096x1024)
    ushort_t* wqkvb = (ushort_t*)(ws + (8ull << 20));    //  6 MB: in_proj_w    (3072x1024)
    ushort_t* woutb = (ushort_t*)(ws + (14ull << 20));   //  2 MB: out_proj_w   (1024x1024)
    ushort_t* w1b   = (ushort_t*)(ws + (16ull << 20));   //  8 MB: w1           (4096x1024)
    ushort_t* w2b   = (ushort_t*)(ws + (24ull << 20));   //  8 MB: w2           (1024x4096)
    ushort_t* qkvb  = (ushort_t*)(ws + (32ull << 20));   // 24 MB: qkv bf16     (4096x3072)
    ushort_t* attnb = (ushort_t*)(ws + (56ull << 20));   //  8 MB: attn bf16    (4096x1024)
    float*    y1    = (float*)(ws + (64ull << 20));      // 16 MB: residual1 / residual2 f32
    float*    x2f   = (float*)(ws + (80ull << 20));      // 16 MB: x2 f32
    ushort_t* x2b   = (ushort_t*)(ws + (96ull << 20));   //  8 MB: x2 bf16
    ushort_t* hb    = (ushort_t*)(ws + (104ull << 20));  // 32 MB: relu hidden  (4096x4096)
    (void)in_sizes; (void)n_in; (void)out_size; (void)ws_size;

    // casts
    cast_f32_bf16<<<4096, 256, 0, stream>>>(x, xb, 1048576);
    cast_f32_bf16<<<3072, 256, 0, stream>>>(in_proj_w, wqkvb, 786432);
    cast_f32_bf16<<<1024, 256, 0, stream>>>(out_proj_w, woutb, 262144);
    cast_f32_bf16<<<4096, 256, 0, stream>>>(w1, w1b, 1048576);
    cast_f32_bf16<<<4096, 256, 0, stream>>>(w2, w2b, 1048576);

    // qkv = x @ in_proj_w.T + b   -> bf16
    gemm_bt<EPI_BIAS | EPI_OUTB><<<dim3(24, 32), 256, 0, stream>>>(
        xb, wqkvb, in_proj_b, nullptr, nullptr, qkvb, 4096, 3072, 1024);

    // banded MFMA flash attention -> attnb bf16
    flash_mfma<<<dim3(32, 16, 2), 256, 0, stream>>>(qkvb, attnb);

    // y1 = x + attn @ out_proj_w.T + b  -> f32
    gemm_bt<EPI_BIAS | EPI_RES | EPI_OUTF><<<dim3(8, 32), 256, 0, stream>>>(
        attnb, woutb, out_proj_b, x, y1, nullptr, 4096, 1024, 1024);

    // x2 = LN1(y1) -> f32 + bf16
    layernorm_k<<<4096, 256, 0, stream>>>(y1, ln1_g, ln1_b, x2f, x2b);

    // h = relu(x2 @ w1.T + b1) -> bf16
    gemm_bt<EPI_BIAS | EPI_RELU | EPI_OUTB><<<dim3(32, 32), 256, 0, stream>>>(
        x2b, w1b, b1, nullptr, nullptr, hb, 4096, 4096, 1024);

    // y2 = x2 + h @ w2.T + b2 -> f32 (reuse y1 buffer)
    gemm_bt<EPI_BIAS | EPI_RES | EPI_OUTF><<<dim3(8, 32), 256, 0, stream>>>(
        hb, w2b, b2, x2f, y1, nullptr, 4096, 1024, 4096);

    // out = LN2(y2) -> f32 d_out
    layernorm_k<<<4096, 256, 0, stream>>>(y1, ln2_g, ln2_b, (float*)d_out, nullptr);
}

// Round 3
// 337.235 us; speedup vs baseline: 2.4071x; 1.0614x over previous
//
#include <hip/hip_runtime.h>
#include <hip/hip_bf16.h>

#define AS1 __attribute__((address_space(1)))
#define AS3 __attribute__((address_space(3)))

typedef __bf16 bf16x8_t __attribute__((ext_vector_type(8)));
typedef float f32x4_t __attribute__((ext_vector_type(4)));
typedef unsigned short ushort_t;
typedef unsigned int uint_t;

static __device__ __forceinline__ ushort_t f2b(float f) {
    __hip_bfloat16 h = __float2bfloat16(f);
    return __builtin_bit_cast(unsigned short, h);
}

// ---------------------------------------------------------------- fused casts (one launch)
struct CastArgs {
    const float* src[5];
    ushort_t* dst[5];
    int cum[6];   // prefix sums of float4-group counts
};

__global__ __launch_bounds__(256) void cast_all(CastArgs a) {
    const int i = blockIdx.x * 256 + threadIdx.x;
    if (i >= a.cum[5]) return;
    int s = 0;
#pragma unroll
    for (int k = 1; k < 5; ++k) s += (i >= a.cum[k]);
    const int idx = i - a.cum[s];
    float4 v = ((const float4*)a.src[s])[idx];
    ushort4 o;
    o.x = f2b(v.x); o.y = f2b(v.y); o.z = f2b(v.z); o.w = f2b(v.w);
    ((ushort4*)a.dst[s])[idx] = o;
}

// ---------------------------------------------------------------- bf16 MFMA GEMM
// C(MxN) = A(MxK) @ B^T (B stored NxK row-major), epilogue per FLAGS.
// Supports split-K over blockIdx.z: each z computes Kc columns starting at
// z*Kc and writes its f32 partial to outs.p[z] (EPI_OUTF without bias/res).
#define EPI_BIAS 1
#define EPI_RELU 2
#define EPI_OUTF 8
#define EPI_OUTB 16

struct P4 { float* p[4]; };

template <int F>
__global__ __launch_bounds__(256, 2) void gemm_bt(const ushort_t* __restrict__ A,
                                                  const ushort_t* __restrict__ B,
                                                  const float* __restrict__ bias,
                                                  P4 outs,
                                                  ushort_t* __restrict__ outb,
                                                  int M, int N, int Kc, int ld) {
    __shared__ ushort_t la[128 * 32];
    __shared__ ushort_t lb[128 * 32];
    const int t = threadIdx.x;
    const int n0 = blockIdx.x * 128;
    const int m0 = blockIdx.y * 128;
    const int z = blockIdx.z;
    const int k0 = z * Kc;
    const int lane = t & 63;
    const int w = t >> 6;
    const int wr = w >> 1, wc = w & 1;
    const int r16 = lane & 15, kq = lane >> 4;

    const int srow = t >> 2;   // 0..63 staging row (+64 for p=1)
    const int scg = t & 3;     // 16B chunk within 32-col row

    f32x4_t acc[4][4] = {};

    const size_t arow0 = (size_t)(m0 + srow) * ld + scg * 8 + k0;
    const size_t brow0 = (size_t)(n0 + srow) * ld + scg * 8 + k0;

    for (int kk = 0; kk < Kc; kk += 32) {
#pragma unroll
        for (int p = 0; p < 2; ++p) {
            const ushort_t* ga = A + arow0 + (size_t)p * 64 * ld + kk;
            const ushort_t* gb = B + brow0 + (size_t)p * 64 * ld + kk;
            __builtin_amdgcn_global_load_lds((AS1 void*)ga, (AS3 void*)(la + (t + 256 * p) * 8), 16, 0, 0);
            __builtin_amdgcn_global_load_lds((AS1 void*)gb, (AS3 void*)(lb + (t + 256 * p) * 8), 16, 0, 0);
        }
        __syncthreads();
        bf16x8_t af[4], bfr[4];
#pragma unroll
        for (int mi = 0; mi < 4; ++mi)
            af[mi] = *(const bf16x8_t*)(la + (wr * 64 + mi * 16 + r16) * 32 + kq * 8);
#pragma unroll
        for (int ni = 0; ni < 4; ++ni)
            bfr[ni] = *(const bf16x8_t*)(lb + (wc * 64 + ni * 16 + r16) * 32 + kq * 8);
#pragma unroll
        for (int mi = 0; mi < 4; ++mi)
#pragma unroll
            for (int ni = 0; ni < 4; ++ni)
                acc[mi][ni] = __builtin_amdgcn_mfma_f32_16x16x32_bf16(af[mi], bfr[ni], acc[mi][ni], 0, 0, 0);
        __syncthreads();
    }

    float* outf = outs.p[z];
#pragma unroll
    for (int mi = 0; mi < 4; ++mi) {
#pragma unroll
        for (int ni = 0; ni < 4; ++ni) {
            const int row = m0 + wr * 64 + mi * 16 + kq * 4;
            const int col = n0 + wc * 64 + ni * 16 + r16;
            float bv = (F & EPI_BIAS) ? bias[col] : 0.f;
#pragma unroll
            for (int i = 0; i < 4; ++i) {
                float v = acc[mi][ni][i] + bv;
                const size_t off = (size_t)(row + i) * N + col;
                if (F & EPI_RELU) v = fmaxf(v, 0.f);
                if (F & EPI_OUTF) outf[off] = v;
                if (F & EPI_OUTB) outb[off] = f2b(v);
            }
        }
    }
}

// ---------------------------------------------------------------- MFMA banded flash attention
// qkv: (B*S, 3072) bf16 rows [q | k | v], head h owns cols h*64..h*64+63 of each third.
__global__ __launch_bounds__(256, 4) void flash_mfma(const ushort_t* __restrict__ qkv,
                                                     ushort_t* __restrict__ attn) {
    const int S = 2048;
    const int h = blockIdx.y, bb = blockIdx.z;
    const int q0 = blockIdx.x * 64;
    const int t = threadIdx.x;
    const int w = t >> 6, lane = t & 63;
    const int r16 = lane & 15, g = lane >> 4;

    __shared__ ushort_t lk[64 * 72];
    __shared__ ushort_t lv[64 * 68];
    __shared__ ushort_t lp[4 * 16 * 72];

    const ushort_t* base = qkv + (size_t)bb * S * 3072 + (size_t)h * 64;

    bf16x8_t qa[2];
    {
        const ushort_t* qrow = base + (size_t)(q0 + 16 * w + r16) * 3072;
        qa[0] = *(const bf16x8_t*)(qrow + g * 8);
        qa[1] = *(const bf16x8_t*)(qrow + 32 + g * 8);
    }

    f32x4_t O[4] = {};
    float mrow[4] = {-1e30f, -1e30f, -1e30f, -1e30f};
    float lrow[4] = {0.f, 0.f, 0.f, 0.f};

    for (int it = 0; it < 5; ++it) {
        const int kt0 = q0 - 128 + 64 * it;
        if (kt0 < 0 || kt0 >= S) continue;

#pragma unroll
        for (int pass = 0; pass < 2; ++pass) {
            const int c = t + 256 * pass;
            const int key = c >> 3, dc = c & 7;
            const ushort_t* src = base + (size_t)(kt0 + key) * 3072 + dc * 8;
            uint4 kk = *(const uint4*)(src + 1024);
            uint4 vv = *(const uint4*)(src + 2048);
            *(uint4*)(lk + key * 72 + dc * 8) = kk;
            uint2* vd = (uint2*)(lv + key * 68 + dc * 8);
            vd[0] = make_uint2(vv.x, vv.y);
            vd[1] = make_uint2(vv.z, vv.w);
        }
        __syncthreads();

        f32x4_t s[4];
#pragma unroll
        for (int sub = 0; sub < 4; ++sub) {
            const ushort_t* krow = lk + (16 * sub + r16) * 72;
            bf16x8_t kb0 = *(const bf16x8_t*)(krow + g * 8);
            bf16x8_t kb1 = *(const bf16x8_t*)(krow + 32 + g * 8);
            f32x4_t z = {};
            z = __builtin_amdgcn_mfma_f32_16x16x32_bf16(qa[0], kb0, z, 0, 0, 0);
            z = __builtin_amdgcn_mfma_f32_16x16x32_bf16(qa[1], kb1, z, 0, 0, 0);
            s[sub] = z;
        }

        float alpha[4];
#pragma unroll
        for (int reg = 0; reg < 4; ++reg) {
            const int i = q0 + 16 * w + g * 4 + reg;
            float rm = -1e30f;
#pragma unroll
            for (int sub = 0; sub < 4; ++sub) {
                const int j = kt0 + 16 * sub + r16;
                const int d = i - j;
                const bool valid = (d <= 128) && (d >= -128);
                float v = valid ? s[sub][reg] * 0.125f : -1e30f;
                s[sub][reg] = v;
                rm = fmaxf(rm, v);
            }
#pragma unroll
            for (int msk = 1; msk < 16; msk <<= 1) rm = fmaxf(rm, __shfl_xor(rm, msk));
            const float mnew = fmaxf(mrow[reg], rm);
            alpha[reg] = __expf(mrow[reg] - mnew);
            mrow[reg] = mnew;
            float rs = 0.f;
#pragma unroll
            for (int sub = 0; sub < 4; ++sub) {
                float p = __expf(s[sub][reg] - mnew);
                s[sub][reg] = p;
                rs += p;
            }
#pragma unroll
            for (int msk = 1; msk < 16; msk <<= 1) rs += __shfl_xor(rs, msk);
            lrow[reg] = lrow[reg] * alpha[reg] + rs;
#pragma unroll
            for (int dd = 0; dd < 4; ++dd) O[dd][reg] *= alpha[reg];
        }

        ushort_t* pw = lp + w * 16 * 72;
#pragma unroll
        for (int sub = 0; sub < 4; ++sub)
#pragma unroll
            for (int reg = 0; reg < 4; ++reg)
                pw[(g * 4 + reg) * 72 + 16 * sub + r16] = f2b(s[sub][reg]);

        bf16x8_t pa0 = *(const bf16x8_t*)(pw + r16 * 72 + g * 8);
        bf16x8_t pa1 = *(const bf16x8_t*)(pw + r16 * 72 + 32 + g * 8);
        const __bf16* lvb = (const __bf16*)lv;
#pragma unroll
        for (int dd = 0; dd < 4; ++dd) {
            bf16x8_t vb0, vb1;
#pragma unroll
            for (int j = 0; j < 8; ++j) {
                vb0[j] = lvb[(g * 8 + j) * 68 + dd * 16 + r16];
                vb1[j] = lvb[(32 + g * 8 + j) * 68 + dd * 16 + r16];
            }
            O[dd] = __builtin_amdgcn_mfma_f32_16x16x32_bf16(pa0, vb0, O[dd], 0, 0, 0);
            O[dd] = __builtin_amdgcn_mfma_f32_16x16x32_bf16(pa1, vb1, O[dd], 0, 0, 0);
        }
        __syncthreads();
    }

#pragma unroll
    for (int reg = 0; reg < 4; ++reg) {
        const float inv = 1.0f / lrow[reg];
        const int i = q0 + 16 * w + g * 4 + reg;
        ushort_t* orow = attn + ((size_t)(bb * S + i)) * 1024 + (size_t)h * 64;
#pragma unroll
        for (int dd = 0; dd < 4; ++dd)
            orow[dd * 16 + r16] = f2b(O[dd][reg] * inv);
    }
}

// ---------------------------------------------------------------- LayerNorm + split-K reduce
// v = sum(partials) + bias + res -> LN -> outf (+ optional outb)
template <int NP>
__global__ __launch_bounds__(256) void ln_red(const float* __restrict__ p0,
                                              const float* __restrict__ p1,
                                              const float* __restrict__ p2,
                                              const float* __restrict__ p3,
                                              const float* __restrict__ bias,
                                              const float* __restrict__ res,
                                              const float* __restrict__ g,
                                              const float* __restrict__ bta,
                                              float* __restrict__ outf,
                                              ushort_t* __restrict__ outb) {
    const int row = blockIdx.x;
    const int t = threadIdx.x;
    const size_t idx = (size_t)row * 256 + t;
    float4 v = ((const float4*)p0)[idx];
    {
        float4 a = ((const float4*)p1)[idx];
        v.x += a.x; v.y += a.y; v.z += a.z; v.w += a.w;
    }
    if (NP == 4) {
        float4 a = ((const float4*)p2)[idx];
        float4 b = ((const float4*)p3)[idx];
        v.x += a.x + b.x; v.y += a.y + b.y; v.z += a.z + b.z; v.w += a.w + b.w;
    }
    {
        float4 bb = ((const float4*)bias)[t];
        float4 rr = ((const float4*)res)[idx];
        v.x += bb.x + rr.x; v.y += bb.y + rr.y; v.z += bb.z + rr.z; v.w += bb.w + rr.w;
    }

    float s = v.x + v.y + v.z + v.w;
    float s2 = v.x * v.x + v.y * v.y + v.z * v.z + v.w * v.w;
#pragma unroll
    for (int off = 32; off > 0; off >>= 1) {
        s += __shfl_down(s, off);
        s2 += __shfl_down(s2, off);
    }
    __shared__ float red[8];
    const int w = t >> 6, lane = t & 63;
    if (lane == 0) { red[w] = s; red[4 + w] = s2; }
    __syncthreads();
    float S1 = red[0] + red[1] + red[2] + red[3];
    float S2 = red[4] + red[5] + red[6] + red[7];
    float mean = S1 * (1.f / 1024.f);
    float var = S2 * (1.f / 1024.f) - mean * mean;
    float r = rsqrtf(var + 1e-5f);
    float4 gg = ((const float4*)g)[t];
    float4 bb = ((const float4*)bta)[t];
    float4 o;
    o.x = (v.x - mean) * r * gg.x + bb.x;
    o.y = (v.y - mean) * r * gg.y + bb.y;
    o.z = (v.z - mean) * r * gg.z + bb.z;
    o.w = (v.w - mean) * r * gg.w + bb.w;
    ((float4*)outf)[idx] = o;
    if (outb) {
        ushort4 ob;
        ob.x = f2b(o.x); ob.y = f2b(o.y); ob.z = f2b(o.z); ob.w = f2b(o.w);
        ((ushort4*)outb)[idx] = ob;
    }
}

// ---------------------------------------------------------------- launch
extern "C" void kernel_launch(void* const* d_in, const int* in_sizes, int n_in,
                              void* d_out, int out_size, void* d_ws, size_t ws_size,
                              hipStream_t stream) {
    const float* x          = (const float*)d_in[0];
    const float* in_proj_w  = (const float*)d_in[1];
    const float* in_proj_b  = (const float*)d_in[2];
    const float* out_proj_w = (const float*)d_in[3];
    const float* out_proj_b = (const float*)d_in[4];
    const float* ln1_g      = (const float*)d_in[5];
    const float* ln1_b      = (const float*)d_in[6];
    const float* w1         = (const float*)d_in[7];
    const float* b1         = (const float*)d_in[8];
    const float* w2         = (const float*)d_in[9];
    const float* b2         = (const float*)d_in[10];
    const float* ln2_g      = (const float*)d_in[11];
    const float* ln2_b      = (const float*)d_in[12];

    char* ws = (char*)d_ws;
    ushort_t* xb    = (ushort_t*)(ws + (0ull << 20));    //  8 MB: x bf16       (4096x1024)
    ushort_t* wqkvb = (ushort_t*)(ws + (8ull << 20));    //  6 MB: in_proj_w    (3072x1024)
    ushort_t* woutb = (ushort_t*)(ws + (14ull << 20));   //  2 MB: out_proj_w   (1024x1024)
    ushort_t* w1b   = (ushort_t*)(ws + (16ull << 20));   //  8 MB: w1           (4096x1024)
    ushort_t* w2b   = (ushort_t*)(ws + (24ull << 20));   //  8 MB: w2           (1024x4096)
    ushort_t* qkvb  = (ushort_t*)(ws + (32ull << 20));   // 24 MB: qkv bf16     (4096x3072)
    ushort_t* attnb = (ushort_t*)(ws + (56ull << 20));   //  8 MB: attn bf16    (4096x1024)
    float*    y1    = (float*)(ws + (64ull << 20));      // 16 MB: partial p0
    float*    x2f   = (float*)(ws + (80ull << 20));      // 16 MB: x2 f32
    ushort_t* x2b   = (ushort_t*)(ws + (96ull << 20));   //  8 MB: x2 bf16
    ushort_t* hb    = (ushort_t*)(ws + (104ull << 20));  // 32 MB: relu hidden  (4096x4096)
    // split-K partials in regions that are dead at their phase:
    float* op_p1  = (float*)(ws + (32ull << 20));        // out_proj p1 (qkvb dead after flash)
    float* f2_p1  = (float*)(ws + (0ull << 20));         // FFN2 p1 (xb/wqkvb/woutb dead)
    float* f2_p2  = (float*)(ws + (32ull << 20));        // FFN2 p2 (qkvb dead)
    float* f2_p3  = (float*)(ws + (48ull << 20));        // FFN2 p3 (qkvb tail + attnb dead)
    (void)in_sizes; (void)n_in; (void)out_size; (void)ws_size;

    // ---- one fused cast launch
    CastArgs ca;
    ca.src[0] = x;  ca.dst[0] = xb;    // 1048576 float4s
    ca.src[1] = in_proj_w;  ca.dst[1] = wqkvb;  // 786432
    ca.src[2] = out_proj_w; ca.dst[2] = woutb;  // 262144
    ca.src[3] = w1; ca.dst[3] = w1b;   // 1048576
    ca.src[4] = w2; ca.dst[4] = w2b;   // 1048576
    ca.cum[0] = 0;
    ca.cum[1] = 1048576;
    ca.cum[2] = 1048576 + 786432;
    ca.cum[3] = 1048576 + 786432 + 262144;
    ca.cum[4] = 1048576 + 786432 + 262144 + 1048576;
    ca.cum[5] = 1048576 + 786432 + 262144 + 1048576 + 1048576;
    cast_all<<<(ca.cum[5] + 255) / 256, 256, 0, stream>>>(ca);

    P4 none = {{nullptr, nullptr, nullptr, nullptr}};

    // qkv = x @ in_proj_w.T + b   -> bf16
    gemm_bt<EPI_BIAS | EPI_OUTB><<<dim3(24, 32, 1), 256, 0, stream>>>(
        xb, wqkvb, in_proj_b, none, qkvb, 4096, 3072, 1024, 1024);

    // banded MFMA flash attention -> attnb bf16
    flash_mfma<<<dim3(32, 16, 2), 256, 0, stream>>>(qkvb, attnb);

    // out_proj split-K x2: partials (no bias/res)
    P4 op = {{y1, op_p1, nullptr, nullptr}};
    gemm_bt<EPI_OUTF><<<dim3(8, 32, 2), 256, 0, stream>>>(
        attnb, woutb, nullptr, op, nullptr, 4096, 1024, 512, 1024);

    // x2 = LN1(p0+p1 + out_proj_b + x) -> f32 + bf16
    ln_red<2><<<4096, 256, 0, stream>>>(y1, op_p1, nullptr, nullptr,
                                        out_proj_b, x, ln1_g, ln1_b, x2f, x2b);

    // h = relu(x2 @ w1.T + b1) -> bf16
    gemm_bt<EPI_BIAS | EPI_RELU | EPI_OUTB><<<dim3(32, 32, 1), 256, 0, stream>>>(
        x2b, w1b, b1, none, hb, 4096, 4096, 1024, 1024);

    // FFN2 split-K x4: partials
    P4 f2 = {{y1, f2_p1, f2_p2, f2_p3}};
    gemm_bt<EPI_OUTF><<<dim3(8, 32, 4), 256, 0, stream>>>(
        hb, w2b, nullptr, f2, nullptr, 4096, 1024, 1024, 4096);

    // out = LN2(p0+p1+p2+p3 + b2 + x2) -> f32 d_out
    ln_red<4><<<4096, 256, 0, stream>>>(y1, f2_p1, f2_p2, f2_p3,
                                        b2, x2f, ln2_g, ln2_b, (float*)d_out, nullptr);
}

// Round 4
// 312.111 us; speedup vs baseline: 2.6009x; 1.0805x over previous
//
#include <hip/hip_runtime.h>
#include <hip/hip_bf16.h>

#define AS1 __attribute__((address_space(1)))
#define AS3 __attribute__((address_space(3)))

typedef __bf16 bf16x8_t __attribute__((ext_vector_type(8)));
typedef float f32x4_t __attribute__((ext_vector_type(4)));
typedef unsigned short ushort_t;
typedef unsigned int uint_t;

static __device__ __forceinline__ ushort_t f2b(float f) {
    __hip_bfloat16 h = __float2bfloat16(f);
    return __builtin_bit_cast(unsigned short, h);
}
static __device__ __forceinline__ float b2f(ushort_t u) {
    return __uint_as_float((uint_t)u << 16);
}

// ---------------------------------------------------------------- fused casts (one launch)
struct CastArgs {
    const float* src[5];
    ushort_t* dst[5];
    int cum[6];   // prefix sums of float4-group counts
};

__global__ __launch_bounds__(256) void cast_all(CastArgs a) {
    const int i = blockIdx.x * 256 + threadIdx.x;
    if (i >= a.cum[5]) return;
    int s = 0;
#pragma unroll
    for (int k = 1; k < 5; ++k) s += (i >= a.cum[k]);
    const int idx = i - a.cum[s];
    float4 v = ((const float4*)a.src[s])[idx];
    ushort4 o;
    o.x = f2b(v.x); o.y = f2b(v.y); o.z = f2b(v.z); o.w = f2b(v.w);
    ((ushort4*)a.dst[s])[idx] = o;
}

// ---------------------------------------------------------------- bf16 MFMA GEMM
// C(MxN) = A(MxK) @ B^T (B stored NxK row-major), epilogue per FLAGS.
// Split-K over blockIdx.z: z computes Kc cols from z*Kc, writes bf16 partial
// to pb.p[z] when EPI_PART. XCD-swizzled block mapping: each XCD owns a
// contiguous m-stripe (ny/8 panels), n varies fastest -> A panels stay L2-hot.
#define EPI_BIAS 1
#define EPI_RELU 2
#define EPI_PART 8
#define EPI_OUTB 16

struct PB { ushort_t* p[4]; };

template <int F>
__global__ __launch_bounds__(256, 2) void gemm_bt(const ushort_t* __restrict__ A,
                                                  const ushort_t* __restrict__ B,
                                                  const float* __restrict__ bias,
                                                  PB pb,
                                                  ushort_t* __restrict__ outb,
                                                  int M, int N, int Kc, int ld) {
    __shared__ ushort_t la[128 * 32];
    __shared__ ushort_t lb[128 * 32];
    const int t = threadIdx.x;

    // XCD-aware swizzle (grid.x*grid.y*grid.z divisible by 8, grid.y by 8)
    const int nx = gridDim.x, ny = gridDim.y, nz = gridDim.z;
    const int lid = blockIdx.x + nx * (blockIdx.y + ny * blockIdx.z);
    const int xcd = lid & 7;
    const int slot = lid >> 3;
    const int n_i = slot % nx;
    const int rest = slot / nx;
    const int z = rest % nz;
    const int m_i = xcd * (ny >> 3) + rest / nz;

    const int n0 = n_i * 128;
    const int m0 = m_i * 128;
    const int k0 = z * Kc;
    const int lane = t & 63;
    const int w = t >> 6;
    const int wr = w >> 1, wc = w & 1;
    const int r16 = lane & 15, kq = lane >> 4;

    const int srow = t >> 2;   // 0..63 staging row (+64 for p=1)
    const int scg = t & 3;     // 16B chunk within 32-col row

    f32x4_t acc[4][4] = {};

    const size_t arow0 = (size_t)(m0 + srow) * ld + scg * 8 + k0;
    const size_t brow0 = (size_t)(n0 + srow) * ld + scg * 8 + k0;

    for (int kk = 0; kk < Kc; kk += 32) {
#pragma unroll
        for (int p = 0; p < 2; ++p) {
            const ushort_t* ga = A + arow0 + (size_t)p * 64 * ld + kk;
            const ushort_t* gb = B + brow0 + (size_t)p * 64 * ld + kk;
            __builtin_amdgcn_global_load_lds((AS1 void*)ga, (AS3 void*)(la + (t + 256 * p) * 8), 16, 0, 0);
            __builtin_amdgcn_global_load_lds((AS1 void*)gb, (AS3 void*)(lb + (t + 256 * p) * 8), 16, 0, 0);
        }
        __syncthreads();
        bf16x8_t af[4], bfr[4];
#pragma unroll
        for (int mi = 0; mi < 4; ++mi)
            af[mi] = *(const bf16x8_t*)(la + (wr * 64 + mi * 16 + r16) * 32 + kq * 8);
#pragma unroll
        for (int ni = 0; ni < 4; ++ni)
            bfr[ni] = *(const bf16x8_t*)(lb + (wc * 64 + ni * 16 + r16) * 32 + kq * 8);
#pragma unroll
        for (int mi = 0; mi < 4; ++mi)
#pragma unroll
            for (int ni = 0; ni < 4; ++ni)
                acc[mi][ni] = __builtin_amdgcn_mfma_f32_16x16x32_bf16(af[mi], bfr[ni], acc[mi][ni], 0, 0, 0);
        __syncthreads();
    }

    ushort_t* po = (F & EPI_PART) ? pb.p[z] : outb;
#pragma unroll
    for (int mi = 0; mi < 4; ++mi) {
#pragma unroll
        for (int ni = 0; ni < 4; ++ni) {
            const int row = m0 + wr * 64 + mi * 16 + kq * 4;
            const int col = n0 + wc * 64 + ni * 16 + r16;
            float bv = (F & EPI_BIAS) ? bias[col] : 0.f;
#pragma unroll
            for (int i = 0; i < 4; ++i) {
                float v = acc[mi][ni][i] + bv;
                const size_t off = (size_t)(row + i) * N + col;
                if (F & EPI_RELU) v = fmaxf(v, 0.f);
                po[off] = f2b(v);
            }
        }
    }
}

// ---------------------------------------------------------------- MFMA banded flash attention
// qkv: (B*S, 3072) bf16 rows [q | k | v], head h owns cols h*64..h*64+63 of each third.
__global__ __launch_bounds__(256, 4) void flash_mfma(const ushort_t* __restrict__ qkv,
                                                     ushort_t* __restrict__ attn) {
    const int S = 2048;
    const int h = blockIdx.y, bb = blockIdx.z;
    const int q0 = blockIdx.x * 64;
    const int t = threadIdx.x;
    const int w = t >> 6, lane = t & 63;
    const int r16 = lane & 15, g = lane >> 4;

    __shared__ ushort_t lk[64 * 72];
    __shared__ ushort_t lv[64 * 68];
    __shared__ ushort_t lp[4 * 16 * 72];

    const ushort_t* base = qkv + (size_t)bb * S * 3072 + (size_t)h * 64;

    bf16x8_t qa[2];
    {
        const ushort_t* qrow = base + (size_t)(q0 + 16 * w + r16) * 3072;
        qa[0] = *(const bf16x8_t*)(qrow + g * 8);
        qa[1] = *(const bf16x8_t*)(qrow + 32 + g * 8);
    }

    f32x4_t O[4] = {};
    float mrow[4] = {-1e30f, -1e30f, -1e30f, -1e30f};
    float lrow[4] = {0.f, 0.f, 0.f, 0.f};

    for (int it = 0; it < 5; ++it) {
        const int kt0 = q0 - 128 + 64 * it;
        if (kt0 < 0 || kt0 >= S) continue;

#pragma unroll
        for (int pass = 0; pass < 2; ++pass) {
            const int c = t + 256 * pass;
            const int key = c >> 3, dc = c & 7;
            const ushort_t* src = base + (size_t)(kt0 + key) * 3072 + dc * 8;
            uint4 kk = *(const uint4*)(src + 1024);
            uint4 vv = *(const uint4*)(src + 2048);
            *(uint4*)(lk + key * 72 + dc * 8) = kk;
            uint2* vd = (uint2*)(lv + key * 68 + dc * 8);
            vd[0] = make_uint2(vv.x, vv.y);
            vd[1] = make_uint2(vv.z, vv.w);
        }
        __syncthreads();

        f32x4_t s[4];
#pragma unroll
        for (int sub = 0; sub < 4; ++sub) {
            const ushort_t* krow = lk + (16 * sub + r16) * 72;
            bf16x8_t kb0 = *(const bf16x8_t*)(krow + g * 8);
            bf16x8_t kb1 = *(const bf16x8_t*)(krow + 32 + g * 8);
            f32x4_t z = {};
            z = __builtin_amdgcn_mfma_f32_16x16x32_bf16(qa[0], kb0, z, 0, 0, 0);
            z = __builtin_amdgcn_mfma_f32_16x16x32_bf16(qa[1], kb1, z, 0, 0, 0);
            s[sub] = z;
        }

        float alpha[4];
#pragma unroll
        for (int reg = 0; reg < 4; ++reg) {
            const int i = q0 + 16 * w + g * 4 + reg;
            float rm = -1e30f;
#pragma unroll
            for (int sub = 0; sub < 4; ++sub) {
                const int j = kt0 + 16 * sub + r16;
                const int d = i - j;
                const bool valid = (d <= 128) && (d >= -128);
                float v = valid ? s[sub][reg] * 0.125f : -1e30f;
                s[sub][reg] = v;
                rm = fmaxf(rm, v);
            }
#pragma unroll
            for (int msk = 1; msk < 16; msk <<= 1) rm = fmaxf(rm, __shfl_xor(rm, msk));
            const float mnew = fmaxf(mrow[reg], rm);
            alpha[reg] = __expf(mrow[reg] - mnew);
            mrow[reg] = mnew;
            float rs = 0.f;
#pragma unroll
            for (int sub = 0; sub < 4; ++sub) {
                float p = __expf(s[sub][reg] - mnew);
                s[sub][reg] = p;
                rs += p;
            }
#pragma unroll
            for (int msk = 1; msk < 16; msk <<= 1) rs += __shfl_xor(rs, msk);
            lrow[reg] = lrow[reg] * alpha[reg] + rs;
#pragma unroll
            for (int dd = 0; dd < 4; ++dd) O[dd][reg] *= alpha[reg];
        }

        ushort_t* pw = lp + w * 16 * 72;
#pragma unroll
        for (int sub = 0; sub < 4; ++sub)
#pragma unroll
            for (int reg = 0; reg < 4; ++reg)
                pw[(g * 4 + reg) * 72 + 16 * sub + r16] = f2b(s[sub][reg]);

        bf16x8_t pa0 = *(const bf16x8_t*)(pw + r16 * 72 + g * 8);
        bf16x8_t pa1 = *(const bf16x8_t*)(pw + r16 * 72 + 32 + g * 8);
        const __bf16* lvb = (const __bf16*)lv;
#pragma unroll
        for (int dd = 0; dd < 4; ++dd) {
            bf16x8_t vb0, vb1;
#pragma unroll
            for (int j = 0; j < 8; ++j) {
                vb0[j] = lvb[(g * 8 + j) * 68 + dd * 16 + r16];
                vb1[j] = lvb[(32 + g * 8 + j) * 68 + dd * 16 + r16];
            }
            O[dd] = __builtin_amdgcn_mfma_f32_16x16x32_bf16(pa0, vb0, O[dd], 0, 0, 0);
            O[dd] = __builtin_amdgcn_mfma_f32_16x16x32_bf16(pa1, vb1, O[dd], 0, 0, 0);
        }
        __syncthreads();
    }

#pragma unroll
    for (int reg = 0; reg < 4; ++reg) {
        const float inv = 1.0f / lrow[reg];
        const int i = q0 + 16 * w + g * 4 + reg;
        ushort_t* orow = attn + ((size_t)(bb * S + i)) * 1024 + (size_t)h * 64;
#pragma unroll
        for (int dd = 0; dd < 4; ++dd)
            orow[dd * 16 + r16] = f2b(O[dd][reg] * inv);
    }
}

// ---------------------------------------------------------------- LayerNorm + split-K reduce
// v = sum(bf16 partials) + bias + res -> LN -> outf (+ optional outb)
template <int NP>
__global__ __launch_bounds__(256) void ln_red(const ushort_t* __restrict__ p0,
                                              const ushort_t* __restrict__ p1,
                                              const ushort_t* __restrict__ p2,
                                              const ushort_t* __restrict__ p3,
                                              const float* __restrict__ bias,
                                              const float* __restrict__ res,
                                              const float* __restrict__ g,
                                              const float* __restrict__ bta,
                                              float* __restrict__ outf,
                                              ushort_t* __restrict__ outb) {
    const int row = blockIdx.x;
    const int t = threadIdx.x;
    const size_t idx = (size_t)row * 256 + t;
    float4 v;
    {
        ushort4 a = ((const ushort4*)p0)[idx];
        ushort4 b = ((const ushort4*)p1)[idx];
        v.x = b2f(a.x) + b2f(b.x);
        v.y = b2f(a.y) + b2f(b.y);
        v.z = b2f(a.z) + b2f(b.z);
        v.w = b2f(a.w) + b2f(b.w);
    }
    if (NP == 4) {
        ushort4 a = ((const ushort4*)p2)[idx];
        ushort4 b = ((const ushort4*)p3)[idx];
        v.x += b2f(a.x) + b2f(b.x);
        v.y += b2f(a.y) + b2f(b.y);
        v.z += b2f(a.z) + b2f(b.z);
        v.w += b2f(a.w) + b2f(b.w);
    }
    {
        float4 bb = ((const float4*)bias)[t];
        float4 rr = ((const float4*)res)[idx];
        v.x += bb.x + rr.x; v.y += bb.y + rr.y; v.z += bb.z + rr.z; v.w += bb.w + rr.w;
    }

    float s = v.x + v.y + v.z + v.w;
    float s2 = v.x * v.x + v.y * v.y + v.z * v.z + v.w * v.w;
#pragma unroll
    for (int off = 32; off > 0; off >>= 1) {
        s += __shfl_down(s, off);
        s2 += __shfl_down(s2, off);
    }
    __shared__ float red[8];
    const int w = t >> 6, lane = t & 63;
    if (lane == 0) { red[w] = s; red[4 + w] = s2; }
    __syncthreads();
    float S1 = red[0] + red[1] + red[2] + red[3];
    float S2 = red[4] + red[5] + red[6] + red[7];
    float mean = S1 * (1.f / 1024.f);
    float var = S2 * (1.f / 1024.f) - mean * mean;
    float r = rsqrtf(var + 1e-5f);
    float4 gg = ((const float4*)g)[t];
    float4 bb = ((const float4*)bta)[t];
    float4 o;
    o.x = (v.x - mean) * r * gg.x + bb.x;
    o.y = (v.y - mean) * r * gg.y + bb.y;
    o.z = (v.z - mean) * r * gg.z + bb.z;
    o.w = (v.w - mean) * r * gg.w + bb.w;
    ((float4*)outf)[idx] = o;
    if (outb) {
        ushort4 ob;
        ob.x = f2b(o.x); ob.y = f2b(o.y); ob.z = f2b(o.z); ob.w = f2b(o.w);
        ((ushort4*)outb)[idx] = ob;
    }
}

// ---------------------------------------------------------------- launch
extern "C" void kernel_launch(void* const* d_in, const int* in_sizes, int n_in,
                              void* d_out, int out_size, void* d_ws, size_t ws_size,
                              hipStream_t stream) {
    const float* x          = (const float*)d_in[0];
    const float* in_proj_w  = (const float*)d_in[1];
    const float* in_proj_b  = (const float*)d_in[2];
    const float* out_proj_w = (const float*)d_in[3];
    const float* out_proj_b = (const float*)d_in[4];
    const float* ln1_g      = (const float*)d_in[5];
    const float* ln1_b      = (const float*)d_in[6];
    const float* w1         = (const float*)d_in[7];
    const float* b1         = (const float*)d_in[8];
    const float* w2         = (const float*)d_in[9];
    const float* b2         = (const float*)d_in[10];
    const float* ln2_g      = (const float*)d_in[11];
    const float* ln2_b      = (const float*)d_in[12];

    char* ws = (char*)d_ws;
    ushort_t* xb    = (ushort_t*)(ws + (0ull << 20));    //  8 MB: x bf16       (4096x1024)
    ushort_t* wqkvb = (ushort_t*)(ws + (8ull << 20));    //  6 MB: in_proj_w    (3072x1024)
    ushort_t* woutb = (ushort_t*)(ws + (14ull << 20));   //  2 MB: out_proj_w   (1024x1024)
    ushort_t* w1b   = (ushort_t*)(ws + (16ull << 20));   //  8 MB: w1           (4096x1024)
    ushort_t* w2b   = (ushort_t*)(ws + (24ull << 20));   //  8 MB: w2           (1024x4096)
    ushort_t* qkvb  = (ushort_t*)(ws + (32ull << 20));   // 24 MB: qkv bf16     (4096x3072)
    ushort_t* attnb = (ushort_t*)(ws + (56ull << 20));   //  8 MB: attn bf16    (4096x1024)
    float*    x2f   = (float*)(ws + (80ull << 20));      // 16 MB: x2 f32
    ushort_t* x2b   = (ushort_t*)(ws + (96ull << 20));   //  8 MB: x2 bf16
    ushort_t* hb    = (ushort_t*)(ws + (104ull << 20));  // 32 MB: relu hidden  (4096x4096)
    // bf16 split-K partials (8 MB each) in regions dead at their phase:
    ushort_t* op_p0 = (ushort_t*)(ws + (64ull << 20));   // out_proj p0
    ushort_t* op_p1 = (ushort_t*)(ws + (72ull << 20));   // out_proj p1
    ushort_t* f2_p0 = (ushort_t*)(ws + (0ull << 20));    // FFN2 p0 (xb dead)
    ushort_t* f2_p1 = (ushort_t*)(ws + (8ull << 20));    // FFN2 p1 (wqkvb dead)
    ushort_t* f2_p2 = (ushort_t*)(ws + (32ull << 20));   // FFN2 p2 (qkvb dead)
    ushort_t* f2_p3 = (ushort_t*)(ws + (40ull << 20));   // FFN2 p3 (qkvb dead)
    (void)in_sizes; (void)n_in; (void)out_size; (void)ws_size;

    // ---- one fused cast launch
    CastArgs ca;
    ca.src[0] = x;  ca.dst[0] = xb;
    ca.src[1] = in_proj_w;  ca.dst[1] = wqkvb;
    ca.src[2] = out_proj_w; ca.dst[2] = woutb;
    ca.src[3] = w1; ca.dst[3] = w1b;
    ca.src[4] = w2; ca.dst[4] = w2b;
    ca.cum[0] = 0;
    ca.cum[1] = 1048576;
    ca.cum[2] = 1048576 + 786432;
    ca.cum[3] = 1048576 + 786432 + 262144;
    ca.cum[4] = 1048576 + 786432 + 262144 + 1048576;
    ca.cum[5] = 1048576 + 786432 + 262144 + 1048576 + 1048576;
    cast_all<<<(ca.cum[5] + 255) / 256, 256, 0, stream>>>(ca);

    PB none = {{nullptr, nullptr, nullptr, nullptr}};

    // qkv = x @ in_proj_w.T + b   -> bf16
    gemm_bt<EPI_BIAS | EPI_OUTB><<<dim3(24, 32, 1), 256, 0, stream>>>(
        xb, wqkvb, in_proj_b, none, qkvb, 4096, 3072, 1024, 1024);

    // banded MFMA flash attention -> attnb bf16
    flash_mfma<<<dim3(32, 16, 2), 256, 0, stream>>>(qkvb, attnb);

    // out_proj split-K x2 -> bf16 partials
    PB op = {{op_p0, op_p1, nullptr, nullptr}};
    gemm_bt<EPI_PART><<<dim3(8, 32, 2), 256, 0, stream>>>(
        attnb, woutb, nullptr, op, nullptr, 4096, 1024, 512, 1024);

    // x2 = LN1(p0+p1 + out_proj_b + x) -> f32 + bf16
    ln_red<2><<<4096, 256, 0, stream>>>(op_p0, op_p1, nullptr, nullptr,
                                        out_proj_b, x, ln1_g, ln1_b, x2f, x2b);

    // h = relu(x2 @ w1.T + b1) -> bf16
    gemm_bt<EPI_BIAS | EPI_RELU | EPI_OUTB><<<dim3(32, 32, 1), 256, 0, stream>>>(
        x2b, w1b, b1, none, hb, 4096, 4096, 1024, 1024);

    // FFN2 split-K x4 -> bf16 partials
    PB f2 = {{f2_p0, f2_p1, f2_p2, f2_p3}};
    gemm_bt<EPI_PART><<<dim3(8, 32, 4), 256, 0, stream>>>(
        hb, w2b, nullptr, f2, nullptr, 4096, 1024, 1024, 4096);

    // out = LN2(p0+p1+p2+p3 + b2 + x2) -> f32 d_out
    ln_red<4><<<4096, 256, 0, stream>>>(f2_p0, f2_p1, f2_p2, f2_p3,
                                        b2, x2f, ln2_g, ln2_b, (float*)d_out, nullptr);
}

// Round 5
// 299.698 us; speedup vs baseline: 2.7086x; 1.0414x over previous
//
#include <hip/hip_runtime.h>
#include <hip/hip_bf16.h>

#define AS1 __attribute__((address_space(1)))
#define AS3 __attribute__((address_space(3)))

typedef __bf16 bf16x8_t __attribute__((ext_vector_type(8)));
typedef float f32x4_t __attribute__((ext_vector_type(4)));
typedef unsigned short ushort_t;
typedef unsigned int uint_t;

static __device__ __forceinline__ ushort_t f2b(float f) {
    __hip_bfloat16 h = __float2bfloat16(f);
    return __builtin_bit_cast(unsigned short, h);
}
static __device__ __forceinline__ float b2f(ushort_t u) {
    return __uint_as_float((uint_t)u << 16);
}

// ---------------------------------------------------------------- fused casts (one launch)
struct CastArgs {
    const float* src[5];
    ushort_t* dst[5];
    int cum[6];   // prefix sums of float4-group counts
};

__global__ __launch_bounds__(256) void cast_all(CastArgs a) {
    const int i = blockIdx.x * 256 + threadIdx.x;
    if (i >= a.cum[5]) return;
    int s = 0;
#pragma unroll
    for (int k = 1; k < 5; ++k) s += (i >= a.cum[k]);
    const int idx = i - a.cum[s];
    float4 v = ((const float4*)a.src[s])[idx];
    ushort4 o;
    o.x = f2b(v.x); o.y = f2b(v.y); o.z = f2b(v.z); o.w = f2b(v.w);
    ((ushort4*)a.dst[s])[idx] = o;
}

// ---------------------------------------------------------------- bf16 MFMA GEMM, BK=64
// C(MxN) = A(MxK) @ B^T (B stored NxK row-major), epilogue per FLAGS.
// BK=64 (32 MFMAs per barrier pair). LDS rows are 64 elems (128 B = all 32
// banks), so frag reads would all alias bank 0; we XOR-swizzle which global
// 16B chunk each lane stages (col3 ^ (row&7)) -- global_load_lds dests stay
// wave-uniform-contiguous, frag reads spread over all banks (2-way = free).
// Split-K over z (writes bf16 partial to pb.p[z] when EPI_PART). XCD swizzle:
// each XCD owns a contiguous m-stripe, n fastest -> A panels L2-hot.
#define EPI_BIAS 1
#define EPI_RELU 2
#define EPI_PART 8
#define EPI_OUTB 16

struct PB { ushort_t* p[4]; };

template <int F>
__global__ __launch_bounds__(256, 2) void gemm_bt(const ushort_t* __restrict__ A,
                                                  const ushort_t* __restrict__ B,
                                                  const float* __restrict__ bias,
                                                  PB pb,
                                                  ushort_t* __restrict__ outb,
                                                  int M, int N, int Kc, int ld) {
    __shared__ ushort_t la[128 * 64];
    __shared__ ushort_t lb[128 * 64];
    const int t = threadIdx.x;

    // XCD-aware swizzle (grid.x*grid.y*grid.z divisible by 8, grid.y by 8)
    const int nx = gridDim.x, ny = gridDim.y, nz = gridDim.z;
    const int lid = blockIdx.x + nx * (blockIdx.y + ny * blockIdx.z);
    const int xcd = lid & 7;
    const int slot = lid >> 3;
    const int n_i = slot % nx;
    const int rest = slot / nx;
    const int z = rest % nz;
    const int m_i = xcd * (ny >> 3) + rest / nz;

    const int n0 = n_i * 128;
    const int m0 = m_i * 128;
    const int k0 = z * Kc;
    const int lane = t & 63;
    const int w = t >> 6;
    const int wr = w >> 1, wc = w & 1;
    const int r16 = lane & 15, kq = lane >> 4;

    f32x4_t acc[4][4] = {};

    // staging source offsets (k-invariant): pass p stages 16B chunk
    // c = t+256p -> LDS slot c; global col-chunk is XOR-swizzled.
    size_t aoff[4], boff[4];
#pragma unroll
    for (int p = 0; p < 4; ++p) {
        const int c = t + 256 * p;
        const int row = c >> 3, cc = c & 7;
        const int gcol = (cc ^ (row & 7)) * 8;
        aoff[p] = (size_t)(m0 + row) * ld + gcol + k0;
        boff[p] = (size_t)(n0 + row) * ld + gcol + k0;
    }

    for (int kk = 0; kk < Kc; kk += 64) {
#pragma unroll
        for (int p = 0; p < 4; ++p) {
            __builtin_amdgcn_global_load_lds((AS1 void*)(A + aoff[p] + kk),
                                             (AS3 void*)(la + (t + 256 * p) * 8), 16, 0, 0);
            __builtin_amdgcn_global_load_lds((AS1 void*)(B + boff[p] + kk),
                                             (AS3 void*)(lb + (t + 256 * p) * 8), 16, 0, 0);
        }
        __syncthreads();
#pragma unroll
        for (int half = 0; half < 2; ++half) {
            const int sw = ((half * 4 + kq) ^ (r16 & 7)) * 8;
            bf16x8_t af[4], bfr[4];
#pragma unroll
            for (int mi = 0; mi < 4; ++mi)
                af[mi] = *(const bf16x8_t*)(la + (wr * 64 + mi * 16 + r16) * 64 + sw);
#pragma unroll
            for (int ni = 0; ni < 4; ++ni)
                bfr[ni] = *(const bf16x8_t*)(lb + (wc * 64 + ni * 16 + r16) * 64 + sw);
#pragma unroll
            for (int mi = 0; mi < 4; ++mi)
#pragma unroll
                for (int ni = 0; ni < 4; ++ni)
                    acc[mi][ni] = __builtin_amdgcn_mfma_f32_16x16x32_bf16(af[mi], bfr[ni], acc[mi][ni], 0, 0, 0);
        }
        __syncthreads();
    }

    ushort_t* po = (F & EPI_PART) ? pb.p[z] : outb;
#pragma unroll
    for (int mi = 0; mi < 4; ++mi) {
#pragma unroll
        for (int ni = 0; ni < 4; ++ni) {
            const int row = m0 + wr * 64 + mi * 16 + kq * 4;
            const int col = n0 + wc * 64 + ni * 16 + r16;
            float bv = (F & EPI_BIAS) ? bias[col] : 0.f;
#pragma unroll
            for (int i = 0; i < 4; ++i) {
                float v = acc[mi][ni][i] + bv;
                const size_t off = (size_t)(row + i) * N + col;
                if (F & EPI_RELU) v = fmaxf(v, 0.f);
                po[off] = f2b(v);
            }
        }
    }
}

// ---------------------------------------------------------------- MFMA banded flash attention
// qkv: (B*S, 3072) bf16 rows [q | k | v], head h owns cols h*64..h*64+63 of each third.
__global__ __launch_bounds__(256, 4) void flash_mfma(const ushort_t* __restrict__ qkv,
                                                     ushort_t* __restrict__ attn) {
    const int S = 2048;
    const int h = blockIdx.y, bb = blockIdx.z;
    const int q0 = blockIdx.x * 64;
    const int t = threadIdx.x;
    const int w = t >> 6, lane = t & 63;
    const int r16 = lane & 15, g = lane >> 4;

    __shared__ ushort_t lk[64 * 72];
    __shared__ ushort_t lv[64 * 68];
    __shared__ ushort_t lp[4 * 16 * 72];

    const ushort_t* base = qkv + (size_t)bb * S * 3072 + (size_t)h * 64;

    bf16x8_t qa[2];
    {
        const ushort_t* qrow = base + (size_t)(q0 + 16 * w + r16) * 3072;
        qa[0] = *(const bf16x8_t*)(qrow + g * 8);
        qa[1] = *(const bf16x8_t*)(qrow + 32 + g * 8);
    }

    f32x4_t O[4] = {};
    float mrow[4] = {-1e30f, -1e30f, -1e30f, -1e30f};
    float lrow[4] = {0.f, 0.f, 0.f, 0.f};

    for (int it = 0; it < 5; ++it) {
        const int kt0 = q0 - 128 + 64 * it;
        if (kt0 < 0 || kt0 >= S) continue;

#pragma unroll
        for (int pass = 0; pass < 2; ++pass) {
            const int c = t + 256 * pass;
            const int key = c >> 3, dc = c & 7;
            const ushort_t* src = base + (size_t)(kt0 + key) * 3072 + dc * 8;
            uint4 kk = *(const uint4*)(src + 1024);
            uint4 vv = *(const uint4*)(src + 2048);
            *(uint4*)(lk + key * 72 + dc * 8) = kk;
            uint2* vd = (uint2*)(lv + key * 68 + dc * 8);
            vd[0] = make_uint2(vv.x, vv.y);
            vd[1] = make_uint2(vv.z, vv.w);
        }
        __syncthreads();

        f32x4_t s[4];
#pragma unroll
        for (int sub = 0; sub < 4; ++sub) {
            const ushort_t* krow = lk + (16 * sub + r16) * 72;
            bf16x8_t kb0 = *(const bf16x8_t*)(krow + g * 8);
            bf16x8_t kb1 = *(const bf16x8_t*)(krow + 32 + g * 8);
            f32x4_t z = {};
            z = __builtin_amdgcn_mfma_f32_16x16x32_bf16(qa[0], kb0, z, 0, 0, 0);
            z = __builtin_amdgcn_mfma_f32_16x16x32_bf16(qa[1], kb1, z, 0, 0, 0);
            s[sub] = z;
        }

        float alpha[4];
#pragma unroll
        for (int reg = 0; reg < 4; ++reg) {
            const int i = q0 + 16 * w + g * 4 + reg;
            float rm = -1e30f;
#pragma unroll
            for (int sub = 0; sub < 4; ++sub) {
                const int j = kt0 + 16 * sub + r16;
                const int d = i - j;
                const bool valid = (d <= 128) && (d >= -128);
                float v = valid ? s[sub][reg] * 0.125f : -1e30f;
                s[sub][reg] = v;
                rm = fmaxf(rm, v);
            }
#pragma unroll
            for (int msk = 1; msk < 16; msk <<= 1) rm = fmaxf(rm, __shfl_xor(rm, msk));
            const float mnew = fmaxf(mrow[reg], rm);
            alpha[reg] = __expf(mrow[reg] - mnew);
            mrow[reg] = mnew;
            float rs = 0.f;
#pragma unroll
            for (int sub = 0; sub < 4; ++sub) {
                float p = __expf(s[sub][reg] - mnew);
                s[sub][reg] = p;
                rs += p;
            }
#pragma unroll
            for (int msk = 1; msk < 16; msk <<= 1) rs += __shfl_xor(rs, msk);
            lrow[reg] = lrow[reg] * alpha[reg] + rs;
#pragma unroll
            for (int dd = 0; dd < 4; ++dd) O[dd][reg] *= alpha[reg];
        }

        ushort_t* pw = lp + w * 16 * 72;
#pragma unroll
        for (int sub = 0; sub < 4; ++sub)
#pragma unroll
            for (int reg = 0; reg < 4; ++reg)
                pw[(g * 4 + reg) * 72 + 16 * sub + r16] = f2b(s[sub][reg]);

        bf16x8_t pa0 = *(const bf16x8_t*)(pw + r16 * 72 + g * 8);
        bf16x8_t pa1 = *(const bf16x8_t*)(pw + r16 * 72 + 32 + g * 8);
        const __bf16* lvb = (const __bf16*)lv;
#pragma unroll
        for (int dd = 0; dd < 4; ++dd) {
            bf16x8_t vb0, vb1;
#pragma unroll
            for (int j = 0; j < 8; ++j) {
                vb0[j] = lvb[(g * 8 + j) * 68 + dd * 16 + r16];
                vb1[j] = lvb[(32 + g * 8 + j) * 68 + dd * 16 + r16];
            }
            O[dd] = __builtin_amdgcn_mfma_f32_16x16x32_bf16(pa0, vb0, O[dd], 0, 0, 0);
            O[dd] = __builtin_amdgcn_mfma_f32_16x16x32_bf16(pa1, vb1, O[dd], 0, 0, 0);
        }
        __syncthreads();
    }

#pragma unroll
    for (int reg = 0; reg < 4; ++reg) {
        const float inv = 1.0f / lrow[reg];
        const int i = q0 + 16 * w + g * 4 + reg;
        ushort_t* orow = attn + ((size_t)(bb * S + i)) * 1024 + (size_t)h * 64;
#pragma unroll
        for (int dd = 0; dd < 4; ++dd)
            orow[dd * 16 + r16] = f2b(O[dd][reg] * inv);
    }
}

// ---------------------------------------------------------------- LayerNorm + split-K reduce
// v = sum(bf16 partials) + bias + res -> LN -> outf (+ optional outb)
template <int NP>
__global__ __launch_bounds__(256) void ln_red(const ushort_t* __restrict__ p0,
                                              const ushort_t* __restrict__ p1,
                                              const ushort_t* __restrict__ p2,
                                              const ushort_t* __restrict__ p3,
                                              const float* __restrict__ bias,
                                              const float* __restrict__ res,
                                              const float* __restrict__ g,
                                              const float* __restrict__ bta,
                                              float* __restrict__ outf,
                                              ushort_t* __restrict__ outb) {
    const int row = blockIdx.x;
    const int t = threadIdx.x;
    const size_t idx = (size_t)row * 256 + t;
    float4 v;
    {
        ushort4 a = ((const ushort4*)p0)[idx];
        ushort4 b = ((const ushort4*)p1)[idx];
        v.x = b2f(a.x) + b2f(b.x);
        v.y = b2f(a.y) + b2f(b.y);
        v.z = b2f(a.z) + b2f(b.z);
        v.w = b2f(a.w) + b2f(b.w);
    }
    if (NP == 4) {
        ushort4 a = ((const ushort4*)p2)[idx];
        ushort4 b = ((const ushort4*)p3)[idx];
        v.x += b2f(a.x) + b2f(b.x);
        v.y += b2f(a.y) + b2f(b.y);
        v.z += b2f(a.z) + b2f(b.z);
        v.w += b2f(a.w) + b2f(b.w);
    }
    {
        float4 bb = ((const float4*)bias)[t];
        float4 rr = ((const float4*)res)[idx];
        v.x += bb.x + rr.x; v.y += bb.y + rr.y; v.z += bb.z + rr.z; v.w += bb.w + rr.w;
    }

    float s = v.x + v.y + v.z + v.w;
    float s2 = v.x * v.x + v.y * v.y + v.z * v.z + v.w * v.w;
#pragma unroll
    for (int off = 32; off > 0; off >>= 1) {
        s += __shfl_down(s, off);
        s2 += __shfl_down(s2, off);
    }
    __shared__ float red[8];
    const int w = t >> 6, lane = t & 63;
    if (lane == 0) { red[w] = s; red[4 + w] = s2; }
    __syncthreads();
    float S1 = red[0] + red[1] + red[2] + red[3];
    float S2 = red[4] + red[5] + red[6] + red[7];
    float mean = S1 * (1.f / 1024.f);
    float var = S2 * (1.f / 1024.f) - mean * mean;
    float r = rsqrtf(var + 1e-5f);
    float4 gg = ((const float4*)g)[t];
    float4 bb = ((const float4*)bta)[t];
    float4 o;
    o.x = (v.x - mean) * r * gg.x + bb.x;
    o.y = (v.y - mean) * r * gg.y + bb.y;
    o.z = (v.z - mean) * r * gg.z + bb.z;
    o.w = (v.w - mean) * r * gg.w + bb.w;
    ((float4*)outf)[idx] = o;
    if (outb) {
        ushort4 ob;
        ob.x = f2b(o.x); ob.y = f2b(o.y); ob.z = f2b(o.z); ob.w = f2b(o.w);
        ((ushort4*)outb)[idx] = ob;
    }
}

// ---------------------------------------------------------------- launch
extern "C" void kernel_launch(void* const* d_in, const int* in_sizes, int n_in,
                              void* d_out, int out_size, void* d_ws, size_t ws_size,
                              hipStream_t stream) {
    const float* x          = (const float*)d_in[0];
    const float* in_proj_w  = (const float*)d_in[1];
    const float* in_proj_b  = (const float*)d_in[2];
    const float* out_proj_w = (const float*)d_in[3];
    const float* out_proj_b = (const float*)d_in[4];
    const float* ln1_g      = (const float*)d_in[5];
    const float* ln1_b      = (const float*)d_in[6];
    const float* w1         = (const float*)d_in[7];
    const float* b1         = (const float*)d_in[8];
    const float* w2         = (const float*)d_in[9];
    const float* b2         = (const float*)d_in[10];
    const float* ln2_g      = (const float*)d_in[11];
    const float* ln2_b      = (const float*)d_in[12];

    char* ws = (char*)d_ws;
    ushort_t* xb    = (ushort_t*)(ws + (0ull << 20));    //  8 MB: x bf16       (4096x1024)
    ushort_t* wqkvb = (ushort_t*)(ws + (8ull << 20));    //  6 MB: in_proj_w    (3072x1024)
    ushort_t* woutb = (ushort_t*)(ws + (14ull << 20));   //  2 MB: out_proj_w   (1024x1024)
    ushort_t* w1b   = (ushort_t*)(ws + (16ull << 20));   //  8 MB: w1           (4096x1024)
    ushort_t* w2b   = (ushort_t*)(ws + (24ull << 20));   //  8 MB: w2           (1024x4096)
    ushort_t* qkvb  = (ushort_t*)(ws + (32ull << 20));   // 24 MB: qkv bf16     (4096x3072)
    ushort_t* attnb = (ushort_t*)(ws + (56ull << 20));   //  8 MB: attn bf16    (4096x1024)
    float*    x2f   = (float*)(ws + (80ull << 20));      // 16 MB: x2 f32
    ushort_t* x2b   = (ushort_t*)(ws + (96ull << 20));   //  8 MB: x2 bf16
    ushort_t* hb    = (ushort_t*)(ws + (104ull << 20));  // 32 MB: relu hidden  (4096x4096)
    // bf16 split-K partials (8 MB each) in regions dead at their phase:
    ushort_t* op_p0 = (ushort_t*)(ws + (64ull << 20));   // out_proj p0
    ushort_t* op_p1 = (ushort_t*)(ws + (72ull << 20));   // out_proj p1
    ushort_t* f2_p0 = (ushort_t*)(ws + (0ull << 20));    // FFN2 p0 (xb dead)
    ushort_t* f2_p1 = (ushort_t*)(ws + (8ull << 20));    // FFN2 p1 (wqkvb dead)
    ushort_t* f2_p2 = (ushort_t*)(ws + (32ull << 20));   // FFN2 p2 (qkvb dead)
    ushort_t* f2_p3 = (ushort_t*)(ws + (40ull << 20));   // FFN2 p3 (qkvb dead)
    (void)in_sizes; (void)n_in; (void)out_size; (void)ws_size;

    // ---- one fused cast launch
    CastArgs ca;
    ca.src[0] = x;  ca.dst[0] = xb;
    ca.src[1] = in_proj_w;  ca.dst[1] = wqkvb;
    ca.src[2] = out_proj_w; ca.dst[2] = woutb;
    ca.src[3] = w1; ca.dst[3] = w1b;
    ca.src[4] = w2; ca.dst[4] = w2b;
    ca.cum[0] = 0;
    ca.cum[1] = 1048576;
    ca.cum[2] = 1048576 + 786432;
    ca.cum[3] = 1048576 + 786432 + 262144;
    ca.cum[4] = 1048576 + 786432 + 262144 + 1048576;
    ca.cum[5] = 1048576 + 786432 + 262144 + 1048576 + 1048576;
    cast_all<<<(ca.cum[5] + 255) / 256, 256, 0, stream>>>(ca);

    PB none = {{nullptr, nullptr, nullptr, nullptr}};

    // qkv = x @ in_proj_w.T + b   -> bf16
    gemm_bt<EPI_BIAS | EPI_OUTB><<<dim3(24, 32, 1), 256, 0, stream>>>(
        xb, wqkvb, in_proj_b, none, qkvb, 4096, 3072, 1024, 1024);

    // banded MFMA flash attention -> attnb bf16
    flash_mfma<<<dim3(32, 16, 2), 256, 0, stream>>>(qkvb, attnb);

    // out_proj split-K x2 -> bf16 partials
    PB op = {{op_p0, op_p1, nullptr, nullptr}};
    gemm_bt<EPI_PART><<<dim3(8, 32, 2), 256, 0, stream>>>(
        attnb, woutb, nullptr, op, nullptr, 4096, 1024, 512, 1024);

    // x2 = LN1(p0+p1 + out_proj_b + x) -> f32 + bf16
    ln_red<2><<<4096, 256, 0, stream>>>(op_p0, op_p1, nullptr, nullptr,
                                        out_proj_b, x, ln1_g, ln1_b, x2f, x2b);

    // h = relu(x2 @ w1.T + b1) -> bf16
    gemm_bt<EPI_BIAS | EPI_RELU | EPI_OUTB><<<dim3(32, 32, 1), 256, 0, stream>>>(
        x2b, w1b, b1, none, hb, 4096, 4096, 1024, 1024);

    // FFN2 split-K x4 -> bf16 partials
    PB f2 = {{f2_p0, f2_p1, f2_p2, f2_p3}};
    gemm_bt<EPI_PART><<<dim3(8, 32, 4), 256, 0, stream>>>(
        hb, w2b, nullptr, f2, nullptr, 4096, 1024, 1024, 4096);

    // out = LN2(p0+p1+p2+p3 + b2 + x2) -> f32 d_out
    ln_red<4><<<4096, 256, 0, stream>>>(f2_p0, f2_p1, f2_p2, f2_p3,
                                        b2, x2f, ln2_g, ln2_b, (float*)d_out, nullptr);
}